// Round 3
// baseline (6163.605 us; speedup 1.0000x reference)
//
#include <hip/hip_runtime.h>

#define T_LEN 16384
#define BATCH 32
#define HID 32
#define CHUNK 32
#define L2E 1.44269504088896340736f

typedef float f2 __attribute__((ext_vector_type(2)));

#if __has_builtin(__builtin_amdgcn_exp2f)
#define EXP2F(x) __builtin_amdgcn_exp2f(x)
#else
#define EXP2F(x) __exp2f(x)
#endif
#if __has_builtin(__builtin_amdgcn_rcpf)
#define RCPF(x) __builtin_amdgcn_rcpf(x)
#else
#define RCPF(x) (1.0f / (x))
#endif

__device__ __forceinline__ float bperm(int byteaddr, float v) {
    return __int_as_float(__builtin_amdgcn_ds_bpermute(byteaddr, __float_as_int(v)));
}
__device__ __forceinline__ f2 splat2(float v) { f2 r; r.x = v; r.y = v; return r; }
__device__ __forceinline__ float sigm(float z) {
    return RCPF(1.0f + EXP2F(-z * L2E));
}
__device__ __forceinline__ float tanh_fast(float z) {
    return fmaf(2.0f, RCPF(1.0f + EXP2F(-2.0f * L2E * z)), -1.0f);
}

// v3: 2 sequences per wave. Lane l = hidden unit j=(l&31) of batch (2*blk + (l>>5)).
// Each lane owns ALL FOUR gate rows of its unit, packed as float2:
//   Wif[k]={W_i[j][k],W_f[j][k]}, Wgo[k]={W_g[j][k],W_o[j][k]}  -> v_pk_fma_f32 dots.
// c,h are lane-local (no cross-lane op on the c/h update — round 1/2's shfl_xor
// was ~120cyc of LDS-pipe latency ON the chain). h all-gather within each half
// via 32 independent ds_bpermute (pipelined; k*4 folds into the offset field).
// One wave per block; waves_per_eu(1,1) so the 128 packed-weight VGPRs stay
// resident (round 1: occupancy-targeted allocator spilled at VGPR=48).
__global__ __launch_bounds__(64) __attribute__((amdgpu_waves_per_eu(1, 1)))
void lstm_seq2_kernel(const float* __restrict__ x,
                      const float* __restrict__ W_ih,
                      const float* __restrict__ W_hh,
                      const float* __restrict__ b_ih,
                      const float* __restrict__ b_hh,
                      const float* __restrict__ W_out,
                      const float* __restrict__ b_out,
                      float* __restrict__ out)
{
    const int blk  = blockIdx.x;          // 16 blocks, 2 batches each
    const int lane = threadIdx.x;
    const int j    = lane & 31;           // hidden unit
    const int half = lane >> 5;           // 0: batch 2blk, 1: batch 2blk+1
    const int myb  = 2 * blk + half;
    const int pbase = (lane & 32) << 2;   // bpermute byte base of this half

    // torch gate rows: i=j, f=32+j, g=64+j, o=96+j
    f2 Wif[HID], Wgo[HID];
    {
        const float* ri = W_hh + (size_t)j * HID;
        const float* rf = W_hh + (size_t)(32 + j) * HID;
        const float* rg = W_hh + (size_t)(64 + j) * HID;
        const float* ro = W_hh + (size_t)(96 + j) * HID;
        #pragma unroll
        for (int k = 0; k < HID; ++k) {
            Wif[k].x = ri[k]; Wif[k].y = rf[k];
            Wgo[k].x = rg[k]; Wgo[k].y = ro[k];
        }
    }
    f2 wih_if, wih_go, b_if, b_go;
    wih_if.x = W_ih[j];      wih_if.y = W_ih[32 + j];
    wih_go.x = W_ih[64 + j]; wih_go.y = W_ih[96 + j];
    b_if.x = b_ih[j]      + b_hh[j];
    b_if.y = b_ih[32 + j] + b_hh[32 + j];
    b_go.x = b_ih[64 + j] + b_hh[64 + j];
    b_go.y = b_ih[96 + j] + b_hh[96 + j];

    const float wout = W_out[j];
    const float bout = b_out[0];

    // phist[s][lane]: y-contribution h_j*w_j for step s in chunk.
    // write banks: (65s+l)%32 -> 2-way across halves (free, m136).
    __shared__ float phist[CHUNK][65];

    float c = 0.0f, h = 0.0f;

    const float* xb = x + (size_t)myb * T_LEN;
    // x chunk register: lane l holds x[myb][t0 + (l&31)] (32 steps/chunk)
    float xcur = xb[j];

    for (int t0 = 0; t0 < T_LEN; t0 += CHUNK) {
        float xnext = (t0 + CHUNK < T_LEN) ? xb[t0 + CHUNK + j] : 0.0f;

        #pragma unroll 4
        for (int s = 0; s < CHUNK; ++s) {
            // per-half broadcast of this step's x (off the h-chain)
            const float xs = bperm(pbase + 4 * s, xcur);

            // gather this half's h vector (32 independent bpermutes)
            float hsv[HID];
            #pragma unroll
            for (int k = 0; k < HID; ++k)
                hsv[k] = bperm(pbase + 4 * k, h);

            // packed dots, 4-way split accumulators per pair
            f2 zif0 = __builtin_elementwise_fma(splat2(xs), wih_if, b_if);
            f2 zgo0 = __builtin_elementwise_fma(splat2(xs), wih_go, b_go);
            f2 zif1 = splat2(0.0f), zif2 = splat2(0.0f), zif3 = splat2(0.0f);
            f2 zgo1 = splat2(0.0f), zgo2 = splat2(0.0f), zgo3 = splat2(0.0f);
            #pragma unroll
            for (int q = 0; q < 8; ++q) {
                zif0 = __builtin_elementwise_fma(splat2(hsv[q     ]), Wif[q     ], zif0);
                zif1 = __builtin_elementwise_fma(splat2(hsv[q +  8]), Wif[q +  8], zif1);
                zif2 = __builtin_elementwise_fma(splat2(hsv[q + 16]), Wif[q + 16], zif2);
                zif3 = __builtin_elementwise_fma(splat2(hsv[q + 24]), Wif[q + 24], zif3);
                zgo0 = __builtin_elementwise_fma(splat2(hsv[q     ]), Wgo[q     ], zgo0);
                zgo1 = __builtin_elementwise_fma(splat2(hsv[q +  8]), Wgo[q +  8], zgo1);
                zgo2 = __builtin_elementwise_fma(splat2(hsv[q + 16]), Wgo[q + 16], zgo2);
                zgo3 = __builtin_elementwise_fma(splat2(hsv[q + 24]), Wgo[q + 24], zgo3);
            }
            const f2 zif = (zif0 + zif1) + (zif2 + zif3);
            const f2 zgo = (zgo0 + zgo1) + (zgo2 + zgo3);

            const float si = sigm(zif.x);
            const float sf = sigm(zif.y);
            const float tg = tanh_fast(zgo.x);
            const float so = sigm(zgo.y);

            c = fmaf(sf, c, si * tg);
            h = so * tanh_fast(c);

            phist[s][lane] = h * wout;
        }

        __syncthreads();  // single wave: cheap; publish phist
        {
            const int s_ = lane & 31;    // step this lane reduces
            const int sq = lane >> 5;    // which batch
            float acc = bout;
            #pragma unroll
            for (int k = 0; k < HID; ++k)
                acc += phist[s_][sq * 32 + k];   // banks (s_+k)%32: conflict-free
            out[(size_t)(2 * blk + sq) * T_LEN + t0 + s_] = acc;
        }
        __syncthreads();  // protect phist before next chunk

        xcur = xnext;
    }
}

extern "C" void kernel_launch(void* const* d_in, const int* in_sizes, int n_in,
                              void* d_out, int out_size, void* d_ws, size_t ws_size,
                              hipStream_t stream) {
    const float* x     = (const float*)d_in[0];
    const float* W_ih  = (const float*)d_in[1];
    const float* W_hh  = (const float*)d_in[2];
    const float* b_ih  = (const float*)d_in[3];
    const float* b_hh  = (const float*)d_in[4];
    const float* W_out = (const float*)d_in[5];
    const float* b_out = (const float*)d_in[6];
    float* out = (float*)d_out;

    lstm_seq2_kernel<<<BATCH / 2, 64, 0, stream>>>(x, W_ih, W_hh, b_ih, b_hh,
                                                   W_out, b_out, out);
}

// Round 5
// 4143.670 us; speedup vs baseline: 1.4875x; 1.4875x over previous
//
#include <hip/hip_runtime.h>

#define T_LEN 16384
#define BATCH 32
#define HID 32
#define L2E 1.44269504088896340736f

#if __has_builtin(__builtin_amdgcn_exp2f)
#define EXP2F(x) __builtin_amdgcn_exp2f(x)
#else
#define EXP2F(x) __exp2f(x)
#endif
#if __has_builtin(__builtin_amdgcn_rcpf)
#define RCPF(x) __builtin_amdgcn_rcpf(x)
#else
#define RCPF(x) (1.0f / (x))
#endif

__device__ __forceinline__ float rlane(float v, int lane) {
    return __int_as_float(__builtin_amdgcn_readlane(__float_as_int(v), lane));
}

// Cross-half exchange: upper lanes receive lower-half values of v.
// gfx950 v_permlane32_swap_b32 is a VALU op (~4 cyc) vs ds_swizzle-based
// __shfl_xor (~120 cyc LDS-pipe latency) — this sits ON the recurrent chain.
// HW convention (established empirically, round 4): the instruction swaps
// vdst lanes[32:63] with vsrc lanes[0:31]; builtin returns {vdst_new, vsrc_new}.
// With both operands = v: r.x (vdst_new) has lanes 32-63 = old lanes 0-31
// -> r.x is the lower->upper ship. (round 4 used r.y: absmax 0.34, upper
// lanes got their own values back — wrong component, now fixed.)
__device__ __forceinline__ float xhalf_lo_to_hi(float v) {
#if __has_builtin(__builtin_amdgcn_permlane32_swap)
    typedef unsigned u2_t __attribute__((ext_vector_type(2)));
    u2_t r = __builtin_amdgcn_permlane32_swap(__float_as_uint(v), __float_as_uint(v),
                                              false, false);
    return __uint_as_float(r.x);
#else
    return __shfl_xor(v, 32, 64);
#endif
}

// Round-1 structure (best measured): one wave per batch, lane j<32 owns gates
// (i_j, g_j); lane 32+j owns (f_j, o_j) + state (c_j, h_j). h broadcast via
// v_readlane -> SGPRs. NO waves_per_eu / asm pins (round 2: -8%, scheduling
// regression; W reloads are chain-independent and hide fine).
// Changes vs round 1: permlane32_swap replaces shfl_xor on the chain;
// 4-way split accumulators remove the 33-deep fmac chain tail.
__global__ __launch_bounds__(64, 1)
void lstm_seq_kernel(const float* __restrict__ x,
                     const float* __restrict__ W_ih,
                     const float* __restrict__ W_hh,
                     const float* __restrict__ b_ih,
                     const float* __restrict__ b_hh,
                     const float* __restrict__ W_out,
                     const float* __restrict__ b_out,
                     float* __restrict__ out)
{
    const int b    = blockIdx.x;
    const int lane = threadIdx.x;
    const int j    = lane & 31;
    const bool upper = (lane >= 32);

    // torch gate order in W_ih/W_hh rows: [0,32)=i [32,64)=f [64,96)=g [96,128)=o
    const int rowA = upper ? (32 + j) : j;        // f : i   (both sigmoid)
    const int rowB = upper ? (96 + j) : (64 + j); // o : g   (sigmoid : tanh)

    float Wa[HID], Wb[HID];
    const float4* Whh4 = reinterpret_cast<const float4*>(W_hh);
    #pragma unroll
    for (int q = 0; q < 8; ++q) {
        float4 va = Whh4[rowA * 8 + q];
        Wa[4*q+0] = va.x; Wa[4*q+1] = va.y; Wa[4*q+2] = va.z; Wa[4*q+3] = va.w;
        float4 vb = Whh4[rowB * 8 + q];
        Wb[4*q+0] = vb.x; Wb[4*q+1] = vb.y; Wb[4*q+2] = vb.z; Wb[4*q+3] = vb.w;
    }
    const float wihA = W_ih[rowA];
    const float wihB = W_ih[rowB];
    const float bA = b_ih[rowA] + b_hh[rowA];
    const float bB = b_ih[rowB] + b_hh[rowB];

    // B-gate activation: r = rcp(1 + exp2(-z*sB)); B = r*mB + aB
    //   lower (g, tanh):    sB = 2*log2e, mB = 2, aB = -1
    //   upper (o, sigmoid): sB =   log2e, mB = 1, aB =  0
    const float sB = upper ? L2E : (2.0f * L2E);
    const float mB = upper ? 1.0f : 2.0f;
    const float aB = upper ? 0.0f : -1.0f;

    const float wout = W_out[j];
    const float bout = b_out[0];

    // Deferred-output history (flushed every 64 steps; off the chain).
    __shared__ float phist[64 * 33];

    float hs[HID];
    #pragma unroll
    for (int k = 0; k < HID; ++k) hs[k] = 0.0f;
    float c = 0.0f;

    const float* xb = x + (size_t)b * T_LEN;
    float*       yb = out + (size_t)b * T_LEN;

    float xv = xb[lane];  // 64 timesteps of x per lane-chunk

    for (int t0 = 0; t0 < T_LEN; t0 += 64) {
        float xv_next = (t0 + 64 < T_LEN) ? xb[t0 + 64 + lane] : 0.0f;

        #pragma unroll 4
        for (int s = 0; s < 64; ++s) {
            const float xs = rlane(xv, s);
            // 4-way split accumulators: 8 independent 8-deep fmac chains ->
            // dot section is issue-bound (~128 cyc), no chain-tail exposure
            float za0 = fmaf(xs, wihA, bA), za1 = 0.0f, za2 = 0.0f, za3 = 0.0f;
            float zb0 = fmaf(xs, wihB, bB), zb1 = 0.0f, zb2 = 0.0f, zb3 = 0.0f;
            #pragma unroll
            for (int q = 0; q < 8; ++q) {
                za0 = fmaf(hs[q     ], Wa[q     ], za0);
                za1 = fmaf(hs[q +  8], Wa[q +  8], za1);
                za2 = fmaf(hs[q + 16], Wa[q + 16], za2);
                za3 = fmaf(hs[q + 24], Wa[q + 24], za3);
                zb0 = fmaf(hs[q     ], Wb[q     ], zb0);
                zb1 = fmaf(hs[q +  8], Wb[q +  8], zb1);
                zb2 = fmaf(hs[q + 16], Wb[q + 16], zb2);
                zb3 = fmaf(hs[q + 24], Wb[q + 24], zb3);
            }
            const float za = (za0 + za1) + (za2 + za3);
            const float zb = (zb0 + zb1) + (zb2 + zb3);

            // A = sigmoid(za)  (i on lower, f on upper)
            const float A  = RCPF(1.0f + EXP2F(-za * L2E));
            const float r  = RCPF(1.0f + EXP2F(-zb * sB));
            const float Bv = fmaf(r, mB, aB);  // tanh(g) : sigmoid(o)

            // lower lanes: u = sig(i)*tanh(g); ship to upper half (VALU swap)
            const float u  = A * Bv;
            const float tu = xhalf_lo_to_hi(u);

            // upper lanes: c = sig(f)*c + u ; h = sig(o)*tanh(c)
            // (lower lanes run the same ops on bounded garbage — harmless)
            c = fmaf(A, c, tu);
            const float th = fmaf(2.0f, RCPF(1.0f + EXP2F(-2.0f * L2E * c)), -1.0f);
            const float h  = Bv * th;

            if (upper) phist[s * 33 + j] = h * wout;

            // broadcast new h to SGPRs for the next step's dots
            #pragma unroll
            for (int k = 0; k < HID; ++k) hs[k] = rlane(h, 32 + k);
        }

        __syncthreads();  // single wave: cheap; publish phist
        float acc = bout;
        #pragma unroll
        for (int k = 0; k < HID; ++k) acc += phist[lane * 33 + k];
        yb[t0 + lane] = acc;
        __syncthreads();  // protect phist before next chunk rewrites it

        xv = xv_next;
    }
}

extern "C" void kernel_launch(void* const* d_in, const int* in_sizes, int n_in,
                              void* d_out, int out_size, void* d_ws, size_t ws_size,
                              hipStream_t stream) {
    const float* x     = (const float*)d_in[0];
    const float* W_ih  = (const float*)d_in[1];
    const float* W_hh  = (const float*)d_in[2];
    const float* b_ih  = (const float*)d_in[3];
    const float* b_hh  = (const float*)d_in[4];
    const float* W_out = (const float*)d_in[5];
    const float* b_out = (const float*)d_in[6];
    float* out = (float*)d_out;

    lstm_seq_kernel<<<BATCH, 64, 0, stream>>>(x, W_ih, W_hh, b_ih, b_hh,
                                              W_out, b_out, out);
}